// Round 5
// baseline (286.151 us; speedup 1.0000x reference)
//
#include <hip/hip_runtime.h>
#include <stdint.h>

#define NROWS 16384
#define D 4096

typedef __bf16 bf16x8 __attribute__((ext_vector_type(8)));
typedef float  f32x4  __attribute__((ext_vector_type(4)));

__device__ inline unsigned short f2bf(float f) {
    unsigned u = __float_as_uint(f);
    u += 0x7fffu + ((u >> 16) & 1u);
    return (unsigned short)(u >> 16);
}

// ---------------- fused Wco build ----------------
// block = (X,Y) of the 16x16 output-mode pair grid; 256 threads.
// c2[z][pqr] = sum_{x,y} fo0[X,x] fo1[Y,y] core[x,y,z,pqr]   (16 KB LDS)
// wco rows n = X*256+Y*16+Z for Z=0..15, stored in the GEMM staging layout:
// element k (=2*kp+{0,1}) of row n -> u32 index ((kp>>2)*4096 + n)*4 + (kp&3)
__global__ __launch_bounds__(256) void k_wco(const float* __restrict__ core,
                                             const float* __restrict__ fo0,
                                             const float* __restrict__ fo1,
                                             const float* __restrict__ fo2,
                                             unsigned int* __restrict__ wco) {
    __shared__ float wxy[64];
    __shared__ float c2[4096];

    const int tid = threadIdx.x;
    const int X = blockIdx.x >> 4, Y = blockIdx.x & 15;

    if (tid < 64) wxy[tid] = fo0[X * 8 + (tid >> 3)] * fo1[Y * 8 + (tid & 7)];
    __syncthreads();

    // c2 compute: thread owns pqr4 = tid&127 (float4), zt = tid>>7, z = 2i+zt
    {
        const int pqr4 = tid & 127, zt = tid >> 7;
        const f32x4* core4 = (const f32x4*)core;
        f32x4 acc[4] = {};
        #pragma unroll 1
        for (int xy = 0; xy < 64; ++xy) {
            const float w = wxy[xy];
            const f32x4* cp = core4 + xy * 1024 + pqr4;
            #pragma unroll
            for (int i = 0; i < 4; ++i)
                acc[i] += w * cp[(2 * i + zt) * 128];
        }
        f32x4* c24 = (f32x4*)c2;
        #pragma unroll
        for (int i = 0; i < 4; ++i)
            c24[(2 * i + zt) * 128 + pqr4] = acc[i];
    }
    __syncthreads();

    // Z-expansion + store: thread = kp (bf16-pair index 0..255)
    {
        const int kp = tid;
        float2 pr[8];
        #pragma unroll
        for (int z = 0; z < 8; ++z) pr[z] = *(const float2*)&c2[z * 512 + 2 * kp];
        const int s = kp >> 2, w = kp & 3;
        const int nbase = X * 256 + Y * 16;
        #pragma unroll
        for (int Z = 0; Z < 16; ++Z) {
            float s0 = 0.f, s1 = 0.f;
            #pragma unroll
            for (int z = 0; z < 8; ++z) {
                const float f = fo2[Z * 8 + z];
                s0 += f * pr[z].x; s1 += f * pr[z].y;
            }
            wco[((size_t)s * 4096 + nbase + Z) * 4 + w] =
                (unsigned)f2bf(s0) | ((unsigned)f2bf(s1) << 16);
        }
    }
}

// ---------------- input contraction: one row per block -> t3 bf16 ----------------
// t3 stored in GEMM staging layout [ks][k4][n][8bf16]
__global__ __launch_bounds__(256, 5) void k_t3(const float* __restrict__ x,
                                               const float* __restrict__ fi0,
                                               const float* __restrict__ fi1,
                                               const float* __restrict__ fi2,
                                               const int* __restrict__ perm,
                                               unsigned int* __restrict__ t3out) {
    __shared__ float xr[4096];    // 16 KB (un-permuted row)
    __shared__ float t1[2048];    //  8 KB
    __shared__ float t2[1024];    //  4 KB
    __shared__ float t3l[512];    //  2 KB

    const int tid = threadIdx.x;
    const int n = blockIdx.x;

    // linear coalesced row load (permutation applied at the step-3 gather)
    const float4* xrow = (const float4*)(x + (size_t)n * D);
    float4* xr4 = (float4*)xr;
    #pragma unroll
    for (int it = 0; it < 4; ++it)
        xr4[it * 256 + tid] = xrow[it * 256 + tid];

    // preload the 16 permutation indices this thread gathers (L1/L2-hot)
    int pj[16];
    #pragma unroll
    for (int a = 0; a < 16; ++a) pj[a] = perm[a * 256 + tid];
    __syncthreads();

    // step 3: t1[p][bc] = sum_a xp[a*256+bc] * fi0[a,p],  xp[i] = xr[perm[i]]
    {
        float a8[8] = {0,0,0,0,0,0,0,0};
        #pragma unroll
        for (int a = 0; a < 16; ++a) {
            float v = xr[pj[a]];
            #pragma unroll
            for (int p = 0; p < 8; ++p) a8[p] += v * fi0[a * 8 + p];
        }
        #pragma unroll
        for (int p = 0; p < 8; ++p) t1[p * 256 + tid] = a8[p];
    }
    __syncthreads();

    // step 4: t2[p][q][c] = sum_b t1[p][b*16+c] * fi1[b,q]   (thread: p,c,q-half)
    {
        const int p = tid >> 5, c = (tid >> 1) & 15, qh = tid & 1;
        float a4[4] = {0,0,0,0};
        #pragma unroll
        for (int b = 0; b < 16; ++b) {
            float v = t1[p * 256 + b * 16 + c];
            #pragma unroll
            for (int qi = 0; qi < 4; ++qi) a4[qi] += v * fi1[b * 8 + qh * 4 + qi];
        }
        #pragma unroll
        for (int qi = 0; qi < 4; ++qi) t2[p * 128 + (qh * 4 + qi) * 16 + c] = a4[qi];
    }
    __syncthreads();

    // step 5: t3[p][q][rr] = sum_c t2[p][q][c] * fi2[c,rr]   (thread: p,q,rr-quarter)
    {
        const int p = tid >> 5, q = (tid >> 2) & 7, rh = tid & 3;
        float a2[2] = {0,0};
        #pragma unroll
        for (int c = 0; c < 16; ++c) {
            float v = t2[p * 128 + q * 16 + c];
            #pragma unroll
            for (int ri = 0; ri < 2; ++ri) a2[ri] += v * fi2[c * 8 + rh * 2 + ri];
        }
        t3l[p * 64 + q * 8 + rh * 2 + 0] = a2[0];
        t3l[p * 64 + q * 8 + rh * 2 + 1] = a2[1];
    }
    __syncthreads();

    // pack to bf16, store in [ks][k4][n][8] layout (pair index = tid, k = 2*tid)
    {
        const int ks = tid >> 5, k4 = (tid >> 2) & 7, w = tid & 3;
        t3out[(((size_t)ks * 8 + k4) * NROWS + n) * 4 + w] =
            (unsigned)f2bf(t3l[2 * tid]) | ((unsigned)f2bf(t3l[2 * tid + 1]) << 16);
    }
}

// ---------------- GEMM: out[n][4096] = t3 @ Wco^T + epilogue ----------------
// 128x128 tile, BK=64, 4 waves (2x2 of 64x64), mfma_f32_16x16x32_bf16.
// Inputs pre-tiled as [ks][k4][row][8] so staging is fully coalesced and the
// LDS image is the proven zero-conflict [k4][row][8] layout.
__global__ __launch_bounds__(256, 4) void k_gemm(const __bf16* __restrict__ t3,
                                                 const __bf16* __restrict__ wco,
                                                 const float* __restrict__ pds,
                                                 const float* __restrict__ alphap,
                                                 const float* __restrict__ bias,
                                                 float* __restrict__ out) {
    __shared__ __bf16 lA[8192];   // [k4 0..7][row 0..127][8]  16 KB
    __shared__ __bf16 lB[8192];   // same for B               16 KB

    const int tid = threadIdx.x, lane = tid & 63, wv = tid >> 6;

    // XCD-chunked bijective swizzle, n fastest (A-panel L2-hot per XCD)
    const int bid = blockIdx.x;
    const int wgid = (bid & 7) * 512 + (bid >> 3);
    const int m0 = (wgid >> 5) * 128;      // 16 contiguous m-panels per XCD
    const int n0 = (wgid & 31) * 128;      // n fastest
    const int wm = wv >> 1, wn = wv & 1;
    const int l15 = lane & 15, l4 = lane >> 4;

    // preload epilogue data (hidden under the K-loop)
    const float alpha = alphap[0];
    float pv[4], bv[4];
    #pragma unroll
    for (int nt = 0; nt < 4; ++nt) {
        const int col = n0 + wn * 64 + nt * 16 + l15;
        pv[nt] = pds[col] * alpha;
        bv[nt] = bias[col];
    }

    f32x4 acc[4][4] = {};

    for (int ks = 0; ks < 8; ++ks) {
        #pragma unroll
        for (int i = 0; i < 4; ++i) {
            const int c = i * 256 + tid;            // 16B chunk id, 0..1023
            const int k4 = c >> 7, r = c & 127;     // k4 wave-uniform, r=lane-contig
            const __bf16* ga = t3 + ((size_t)(ks * 8 + k4) * NROWS + m0 + r) * 8;
            __builtin_amdgcn_global_load_lds(
                (const __attribute__((address_space(1))) void*)ga,
                (__attribute__((address_space(3))) void*)(lA + (size_t)c * 8),
                16, 0, 0);
            const __bf16* gb = wco + ((size_t)(ks * 8 + k4) * 4096 + n0 + r) * 8;
            __builtin_amdgcn_global_load_lds(
                (const __attribute__((address_space(1))) void*)gb,
                (__attribute__((address_space(3))) void*)(lB + (size_t)c * 8),
                16, 0, 0);
        }
        __syncthreads();
        #pragma unroll
        for (int kk = 0; kk < 2; ++kk) {
            const int k4f = kk * 4 + l4;
            bf16x8 af[4], bfr[4];
            #pragma unroll
            for (int mt = 0; mt < 4; ++mt)
                af[mt] = *(const bf16x8*)&lA[(k4f * 128 + wm * 64 + mt * 16 + l15) * 8];
            #pragma unroll
            for (int nt = 0; nt < 4; ++nt)
                bfr[nt] = *(const bf16x8*)&lB[(k4f * 128 + wn * 64 + nt * 16 + l15) * 8];
            #pragma unroll
            for (int mt = 0; mt < 4; ++mt)
                #pragma unroll
                for (int nt = 0; nt < 4; ++nt)
                    acc[mt][nt] = __builtin_amdgcn_mfma_f32_16x16x32_bf16(
                        af[mt], bfr[nt], acc[mt][nt], 0, 0, 0);
        }
        __syncthreads();
    }

    // epilogue: scale * alpha + bias
    #pragma unroll
    for (int nt = 0; nt < 4; ++nt) {
        const int col = n0 + wn * 64 + nt * 16 + l15;
        #pragma unroll
        for (int mt = 0; mt < 4; ++mt) {
            const int row = m0 + wm * 64 + mt * 16 + l4 * 4;
            #pragma unroll
            for (int j = 0; j < 4; ++j)
                out[(size_t)(row + j) * 4096 + col] = acc[mt][nt][j] * pv[nt] + bv[nt];
        }
    }
}

extern "C" void kernel_launch(void* const* d_in, const int* in_sizes, int n_in,
                              void* d_out, int out_size, void* d_ws, size_t ws_size,
                              hipStream_t stream) {
    const float* x     = (const float*)d_in[0];
    const float* core  = (const float*)d_in[1];
    const float* fi0   = (const float*)d_in[2];
    const float* fi1   = (const float*)d_in[3];
    const float* fi2   = (const float*)d_in[4];
    const float* fo0   = (const float*)d_in[5];
    const float* fo1   = (const float*)d_in[6];
    const float* fo2   = (const float*)d_in[7];
    const float* pds   = (const float*)d_in[8];
    const float* alpha = (const float*)d_in[9];
    const float* bias  = (const float*)d_in[10];
    const int*   perm  = (const int*)d_in[11];
    float* outp = (float*)d_out;

    char* ws = (char*)d_ws;
    unsigned int* wco  = (unsigned int*)(ws);                // 4 MB
    unsigned int* t3ws = (unsigned int*)(ws + 4194304);      // 16 MB

    k_wco<<<256, 256, 0, stream>>>(core, fo0, fo1, fo2, wco);
    k_t3<<<NROWS, 256, 0, stream>>>(x, fi0, fi1, fi2, perm, t3ws);
    k_gemm<<<4096, 256, 0, stream>>>((const __bf16*)t3ws, (const __bf16*)wco,
                                     pds, alpha, bias, outp);
}

// Round 6
// 272.559 us; speedup vs baseline: 1.0499x; 1.0499x over previous
//
#include <hip/hip_runtime.h>
#include <stdint.h>

#define NROWS 16384
#define D 4096

typedef __bf16 bf16x8 __attribute__((ext_vector_type(8)));
typedef float  f32x4  __attribute__((ext_vector_type(4)));

__device__ inline unsigned short f2bf(float f) {
    unsigned u = __float_as_uint(f);
    u += 0x7fffu + ((u >> 16) & 1u);
    return (unsigned short)(u >> 16);
}

// ---------------- setup: inverse permutation ----------------
__global__ __launch_bounds__(256) void k_inv_perm(const int* __restrict__ perm,
                                                  int* __restrict__ inv) {
    int d = blockIdx.x * blockDim.x + threadIdx.x;
    if (d < D) inv[perm[d]] = d;
}

// ---------------- Wco build: c1[X][y][z][pqr] = sum_x fo0[X,x] core[x,y,z,pqr]
__global__ __launch_bounds__(256) void k_b1(const float* __restrict__ core,
                                            const float* __restrict__ fo0,
                                            float* __restrict__ c1) {
    int g = blockIdx.x * 256 + threadIdx.x;      // 524288
    int pqr = g & 511, z = (g >> 9) & 7, y = (g >> 12) & 7, X = g >> 15;
    float s = 0.f;
    #pragma unroll
    for (int x = 0; x < 8; ++x)
        s += fo0[X * 8 + x] * core[x * 32768 + y * 4096 + z * 512 + pqr];
    c1[g] = s;
}

// c2[X][Y][z][pqr] = sum_y fo1[Y,y] c1[X,y,z,pqr]
__global__ __launch_bounds__(256) void k_b2(const float* __restrict__ c1,
                                            const float* __restrict__ fo1,
                                            float* __restrict__ c2) {
    int g = blockIdx.x * 256 + threadIdx.x;      // 1048576
    int pqr = g & 511, z = (g >> 9) & 7, Y = (g >> 12) & 15, X = g >> 16;
    float s = 0.f;
    #pragma unroll
    for (int y = 0; y < 8; ++y)
        s += fo1[Y * 8 + y] * c1[X * 32768 + y * 4096 + z * 512 + pqr];
    c2[g] = s;
}

// Wco in GEMM staging layout [ks][k4][n][8bf16] (u32-pair granularity):
// element k of row n lives at ((ks*8+k4)*4096 + n)*8 + (k&7), ks=k>>6, k4=(k>>3)&7
__global__ __launch_bounds__(256) void k_b3(const float* __restrict__ c2,
                                            const float* __restrict__ fo2,
                                            unsigned int* __restrict__ wco) {
    int g = blockIdx.x * 256 + threadIdx.x;      // 1048576
    int kp = g & 255, n = g >> 8;                // kp = bf16-pair index, k=2*kp
    int X = n >> 8, Y = (n >> 4) & 15, Z = n & 15;
    float s0 = 0.f, s1 = 0.f;
    #pragma unroll
    for (int z = 0; z < 8; ++z) {
        float2 v = *(const float2*)&c2[X * 65536 + Y * 4096 + z * 512 + 2 * kp];
        float f = fo2[Z * 8 + z];
        s0 += f * v.x; s1 += f * v.y;
    }
    const int ks = kp >> 5, k4 = (kp >> 2) & 7, w = kp & 3;
    wco[(((size_t)ks * 8 + k4) * 4096 + n) * 4 + w] =
        (unsigned)f2bf(s0) | ((unsigned)f2bf(s1) << 16);
}

// ---------------- input contraction: one row per block -> t3 bf16 ----------------
// t3 stored in GEMM staging layout [ks][k4][n][8bf16]
__global__ __launch_bounds__(256, 4) void k_t3(const float* __restrict__ x,
                                               const float* __restrict__ fi0,
                                               const float* __restrict__ fi1,
                                               const float* __restrict__ fi2,
                                               const int* __restrict__ inv,
                                               unsigned int* __restrict__ t3out) {
    __shared__ float xr[4096];    // 16 KB
    __shared__ float t1[2048];    //  8 KB
    __shared__ float t2[1024];    //  4 KB
    __shared__ float t3l[512];    //  2 KB

    const int tid = threadIdx.x;
    const int n = blockIdx.x;

    // coalesced row load + permuted scatter into LDS
    const float4* xrow = (const float4*)(x + (size_t)n * D);
    #pragma unroll
    for (int it = 0; it < 4; ++it) {
        float4 v = xrow[tid + it * 256];
        int4  iv = ((const int4*)inv)[tid + it * 256];
        xr[iv.x] = v.x; xr[iv.y] = v.y; xr[iv.z] = v.z; xr[iv.w] = v.w;
    }
    __syncthreads();

    // step 3: t1[p][bc] = sum_a xr[a*256+bc] * fi0[a,p]
    {
        float a8[8] = {0,0,0,0,0,0,0,0};
        #pragma unroll
        for (int a = 0; a < 16; ++a) {
            float v = xr[a * 256 + tid];
            #pragma unroll
            for (int p = 0; p < 8; ++p) a8[p] += v * fi0[a * 8 + p];
        }
        #pragma unroll
        for (int p = 0; p < 8; ++p) t1[p * 256 + tid] = a8[p];
    }
    __syncthreads();

    // step 4: t2[p][q][c] = sum_b t1[p][b*16+c] * fi1[b,q]   (thread: p,c,q-half)
    {
        const int p = tid >> 5, c = (tid >> 1) & 15, qh = tid & 1;
        float a4[4] = {0,0,0,0};
        #pragma unroll
        for (int b = 0; b < 16; ++b) {
            float v = t1[p * 256 + b * 16 + c];
            #pragma unroll
            for (int qi = 0; qi < 4; ++qi) a4[qi] += v * fi1[b * 8 + qh * 4 + qi];
        }
        #pragma unroll
        for (int qi = 0; qi < 4; ++qi) t2[p * 128 + (qh * 4 + qi) * 16 + c] = a4[qi];
    }
    __syncthreads();

    // step 5: t3[p][q][rr] = sum_c t2[p][q][c] * fi2[c,rr]   (thread: p,q,rr-quarter)
    {
        const int p = tid >> 5, q = (tid >> 2) & 7, rh = tid & 3;
        float a2[2] = {0,0};
        #pragma unroll
        for (int c = 0; c < 16; ++c) {
            float v = t2[p * 128 + q * 16 + c];
            #pragma unroll
            for (int ri = 0; ri < 2; ++ri) a2[ri] += v * fi2[c * 8 + rh * 2 + ri];
        }
        t3l[p * 64 + q * 8 + rh * 2 + 0] = a2[0];
        t3l[p * 64 + q * 8 + rh * 2 + 1] = a2[1];
    }
    __syncthreads();

    // pack to bf16, store in [ks][k4][n][8] layout (pair index = tid, k = 2*tid)
    {
        const int ks = tid >> 5, k4 = (tid >> 2) & 7, w = tid & 3;
        t3out[(((size_t)ks * 8 + k4) * NROWS + n) * 4 + w] =
            (unsigned)f2bf(t3l[2 * tid]) | ((unsigned)f2bf(t3l[2 * tid + 1]) << 16);
    }
}

// ---------------- GEMM: out[n][4096] = t3 @ Wco^T + epilogue ----------------
// 128x128 tile, BK=64, 4 waves (2x2 of 64x64), mfma_f32_16x16x32_bf16.
// 2-phase double-buffered K-loop (T3 minimum recipe): stage tile ks+1 into
// the other LDS buffer FIRST, then ds_read+MFMA on tile ks, then one barrier
// per K-step (its vmcnt drain overlaps the MFMA work). Inputs pre-tiled as
// [ks][k4][row][8] so staging is coalesced and LDS reads are conflict-free.
__global__ __launch_bounds__(256, 2) void k_gemm(const __bf16* __restrict__ t3,
                                                 const __bf16* __restrict__ wco,
                                                 const float* __restrict__ pds,
                                                 const float* __restrict__ alphap,
                                                 const float* __restrict__ bias,
                                                 float* __restrict__ out) {
    __shared__ __bf16 lA[2][8192];   // [buf][k4 0..7][row 0..127][8]  2x16 KB
    __shared__ __bf16 lB[2][8192];   //                                2x16 KB

    const int tid = threadIdx.x, lane = tid & 63, wv = tid >> 6;

    // XCD-chunked bijective swizzle, n fastest (A-panel L2-hot per XCD)
    const int bid = blockIdx.x;
    const int wgid = (bid & 7) * 512 + (bid >> 3);
    const int m0 = (wgid >> 5) * 128;      // 16 contiguous m-panels per XCD
    const int n0 = (wgid & 31) * 128;      // n fastest
    const int wm = wv >> 1, wn = wv & 1;
    const int l15 = lane & 15, l4 = lane >> 4;

    // preload epilogue data (hidden under the K-loop)
    const float alpha = alphap[0];
    float pv[4], bv[4];
    #pragma unroll
    for (int nt = 0; nt < 4; ++nt) {
        const int col = n0 + wn * 64 + nt * 16 + l15;
        pv[nt] = pds[col] * alpha;
        bv[nt] = bias[col];
    }

    // staging: 16 B per lane, fully coalesced; LDS dest linear
    auto stage = [&](int b, int ks) {
        #pragma unroll
        for (int i = 0; i < 4; ++i) {
            const int c = i * 256 + tid;            // 16B chunk id, 0..1023
            const int k4 = c >> 7, r = c & 127;     // k4 wave-uniform, r=lane-contig
            const __bf16* ga = t3 + ((size_t)(ks * 8 + k4) * NROWS + m0 + r) * 8;
            __builtin_amdgcn_global_load_lds(
                (const __attribute__((address_space(1))) void*)ga,
                (__attribute__((address_space(3))) void*)(&lA[b][(size_t)c * 8]),
                16, 0, 0);
            const __bf16* gb = wco + ((size_t)(ks * 8 + k4) * 4096 + n0 + r) * 8;
            __builtin_amdgcn_global_load_lds(
                (const __attribute__((address_space(1))) void*)gb,
                (__attribute__((address_space(3))) void*)(&lB[b][(size_t)c * 8]),
                16, 0, 0);
        }
    };

    f32x4 acc[4][4] = {};

    stage(0, 0);
    __syncthreads();                 // prologue drain (exposed once)

    #pragma unroll 1
    for (int ks = 0; ks < 8; ++ks) {
        const int cur = ks & 1;
        if (ks < 7) stage(cur ^ 1, ks + 1);   // prefetch next tile first
        #pragma unroll
        for (int kk = 0; kk < 2; ++kk) {
            const int k4f = kk * 4 + l4;
            bf16x8 af[4], bfr[4];
            #pragma unroll
            for (int mt = 0; mt < 4; ++mt)
                af[mt] = *(const bf16x8*)&lA[cur][(k4f * 128 + wm * 64 + mt * 16 + l15) * 8];
            #pragma unroll
            for (int nt = 0; nt < 4; ++nt)
                bfr[nt] = *(const bf16x8*)&lB[cur][(k4f * 128 + wn * 64 + nt * 16 + l15) * 8];
            #pragma unroll
            for (int mt = 0; mt < 4; ++mt)
                #pragma unroll
                for (int nt = 0; nt < 4; ++nt)
                    acc[mt][nt] = __builtin_amdgcn_mfma_f32_16x16x32_bf16(
                        af[mt], bfr[nt], acc[mt][nt], 0, 0, 0);
        }
        __syncthreads();             // one barrier/step: drains prefetch, fences buffer reuse
    }

    // epilogue: scale * alpha + bias
    #pragma unroll
    for (int nt = 0; nt < 4; ++nt) {
        const int col = n0 + wn * 64 + nt * 16 + l15;
        #pragma unroll
        for (int mt = 0; mt < 4; ++mt) {
            const int row = m0 + wm * 64 + mt * 16 + l4 * 4;
            #pragma unroll
            for (int j = 0; j < 4; ++j)
                out[(size_t)(row + j) * 4096 + col] = acc[mt][nt][j] * pv[nt] + bv[nt];
        }
    }
}

extern "C" void kernel_launch(void* const* d_in, const int* in_sizes, int n_in,
                              void* d_out, int out_size, void* d_ws, size_t ws_size,
                              hipStream_t stream) {
    const float* x     = (const float*)d_in[0];
    const float* core  = (const float*)d_in[1];
    const float* fi0   = (const float*)d_in[2];
    const float* fi1   = (const float*)d_in[3];
    const float* fi2   = (const float*)d_in[4];
    const float* fo0   = (const float*)d_in[5];
    const float* fo1   = (const float*)d_in[6];
    const float* fo2   = (const float*)d_in[7];
    const float* pds   = (const float*)d_in[8];
    const float* alpha = (const float*)d_in[9];
    const float* bias  = (const float*)d_in[10];
    const int*   perm  = (const int*)d_in[11];
    float* outp = (float*)d_out;

    char* ws = (char*)d_ws;
    int*          inv  = (int*)(ws);                         // 16 KB
    float*        c1   = (float*)(ws + 16384);               // 2 MB
    float*        c2   = (float*)(ws + 16384 + 2097152);     // 4 MB
    unsigned int* wco  = (unsigned int*)(ws + 16384 + 2097152 + 4194304);   // 4 MB
    unsigned int* t3ws = (unsigned int*)(ws + 16384 + 2097152 + 8388608);   // 16 MB

    k_inv_perm<<<16, 256, 0, stream>>>(perm, inv);
    k_b1<<<2048, 256, 0, stream>>>(core, fo0, c1);
    k_b2<<<4096, 256, 0, stream>>>(c1, fo1, c2);
    k_b3<<<4096, 256, 0, stream>>>(c2, fo2, wco);
    k_t3<<<NROWS, 256, 0, stream>>>(x, fi0, fi1, fi2, inv, t3ws);
    k_gemm<<<4096, 256, 0, stream>>>((const __bf16*)t3ws, (const __bf16*)wco,
                                     pds, alpha, bias, outp);
}

// Round 7
// 259.448 us; speedup vs baseline: 1.1029x; 1.0505x over previous
//
#include <hip/hip_runtime.h>
#include <stdint.h>

#define NROWS 16384
#define D 4096

typedef __bf16 bf16x8 __attribute__((ext_vector_type(8)));
typedef float  f32x4  __attribute__((ext_vector_type(4)));

__device__ inline unsigned short f2bf(float f) {
    unsigned u = __float_as_uint(f);
    u += 0x7fffu + ((u >> 16) & 1u);
    return (unsigned short)(u >> 16);
}

// ---------------- setup: inverse permutation ----------------
__global__ __launch_bounds__(256) void k_inv_perm(const int* __restrict__ perm,
                                                  int* __restrict__ inv) {
    int d = blockIdx.x * blockDim.x + threadIdx.x;
    if (d < D) inv[perm[d]] = d;
}

// ---------------- Wco build: c1[X][y][z][pqr] = sum_x fo0[X,x] core[x,y,z,pqr]
__global__ __launch_bounds__(256) void k_b1(const float* __restrict__ core,
                                            const float* __restrict__ fo0,
                                            float* __restrict__ c1) {
    int g = blockIdx.x * 256 + threadIdx.x;      // 524288
    int pqr = g & 511, z = (g >> 9) & 7, y = (g >> 12) & 7, X = g >> 15;
    float s = 0.f;
    #pragma unroll
    for (int x = 0; x < 8; ++x)
        s += fo0[X * 8 + x] * core[x * 32768 + y * 4096 + z * 512 + pqr];
    c1[g] = s;
}

// c2[X][Y][z][pqr] = sum_y fo1[Y,y] c1[X,y,z,pqr]
__global__ __launch_bounds__(256) void k_b2(const float* __restrict__ c1,
                                            const float* __restrict__ fo1,
                                            float* __restrict__ c2) {
    int g = blockIdx.x * 256 + threadIdx.x;      // 1048576
    int pqr = g & 511, z = (g >> 9) & 7, Y = (g >> 12) & 15, X = g >> 16;
    float s = 0.f;
    #pragma unroll
    for (int y = 0; y < 8; ++y)
        s += fo1[Y * 8 + y] * c1[X * 32768 + y * 4096 + z * 512 + pqr];
    c2[g] = s;
}

// Wco in GEMM staging layout [kt][k4][n][8bf16] (u32-pair granularity):
// element k of row n lives at ((kt*8+k4)*4096 + n)*8 + (k&7), kt=k>>6, k4=(k>>3)&7
__global__ __launch_bounds__(256) void k_b3(const float* __restrict__ c2,
                                            const float* __restrict__ fo2,
                                            unsigned int* __restrict__ wco) {
    int g = blockIdx.x * 256 + threadIdx.x;      // 1048576
    int kp = g & 255, n = g >> 8;                // kp = bf16-pair index, k=2*kp
    int X = n >> 8, Y = (n >> 4) & 15, Z = n & 15;
    float s0 = 0.f, s1 = 0.f;
    #pragma unroll
    for (int z = 0; z < 8; ++z) {
        float2 v = *(const float2*)&c2[X * 65536 + Y * 4096 + z * 512 + 2 * kp];
        float f = fo2[Z * 8 + z];
        s0 += f * v.x; s1 += f * v.y;
    }
    const int kt = kp >> 5, k4 = (kp >> 2) & 7, w = kp & 3;
    wco[(((size_t)kt * 8 + k4) * 4096 + n) * 4 + w] =
        (unsigned)f2bf(s0) | ((unsigned)f2bf(s1) << 16);
}

// ---------------- input contraction: one row per block -> t3 bf16 ----------------
// t3 stored in GEMM staging layout [kt][k4][n][8bf16]
__global__ __launch_bounds__(256, 4) void k_t3(const float* __restrict__ x,
                                               const float* __restrict__ fi0,
                                               const float* __restrict__ fi1,
                                               const float* __restrict__ fi2,
                                               const int* __restrict__ inv,
                                               unsigned int* __restrict__ t3out) {
    __shared__ float xr[4096];    // 16 KB
    __shared__ float t1[2048];    //  8 KB
    __shared__ float t2[1024];    //  4 KB
    __shared__ float t3l[512];    //  2 KB

    const int tid = threadIdx.x;
    const int n = blockIdx.x;

    // coalesced row load + permuted scatter into LDS
    const float4* xrow = (const float4*)(x + (size_t)n * D);
    #pragma unroll
    for (int it = 0; it < 4; ++it) {
        float4 v = xrow[tid + it * 256];
        int4  iv = ((const int4*)inv)[tid + it * 256];
        xr[iv.x] = v.x; xr[iv.y] = v.y; xr[iv.z] = v.z; xr[iv.w] = v.w;
    }
    __syncthreads();

    // step 3: t1[p][bc] = sum_a xr[a*256+bc] * fi0[a,p]
    {
        float a8[8] = {0,0,0,0,0,0,0,0};
        #pragma unroll
        for (int a = 0; a < 16; ++a) {
            float v = xr[a * 256 + tid];
            #pragma unroll
            for (int p = 0; p < 8; ++p) a8[p] += v * fi0[a * 8 + p];
        }
        #pragma unroll
        for (int p = 0; p < 8; ++p) t1[p * 256 + tid] = a8[p];
    }
    __syncthreads();

    // step 4: t2[p][q][c] = sum_b t1[p][b*16+c] * fi1[b,q]   (thread: p,c,q-half)
    {
        const int p = tid >> 5, c = (tid >> 1) & 15, qh = tid & 1;
        float a4[4] = {0,0,0,0};
        #pragma unroll
        for (int b = 0; b < 16; ++b) {
            float v = t1[p * 256 + b * 16 + c];
            #pragma unroll
            for (int qi = 0; qi < 4; ++qi) a4[qi] += v * fi1[b * 8 + qh * 4 + qi];
        }
        #pragma unroll
        for (int qi = 0; qi < 4; ++qi) t2[p * 128 + (qh * 4 + qi) * 16 + c] = a4[qi];
    }
    __syncthreads();

    // step 5: t3[p][q][rr] = sum_c t2[p][q][c] * fi2[c,rr]   (thread: p,q,rr-quarter)
    {
        const int p = tid >> 5, q = (tid >> 2) & 7, rh = tid & 3;
        float a2[2] = {0,0};
        #pragma unroll
        for (int c = 0; c < 16; ++c) {
            float v = t2[p * 128 + q * 16 + c];
            #pragma unroll
            for (int ri = 0; ri < 2; ++ri) a2[ri] += v * fi2[c * 8 + rh * 2 + ri];
        }
        t3l[p * 64 + q * 8 + rh * 2 + 0] = a2[0];
        t3l[p * 64 + q * 8 + rh * 2 + 1] = a2[1];
    }
    __syncthreads();

    // pack to bf16, store in [kt][k4][n][8] layout (pair index = tid, k = 2*tid)
    {
        const int kt = tid >> 5, k4 = (tid >> 2) & 7, w = tid & 3;
        t3out[(((size_t)kt * 8 + k4) * NROWS + n) * 4 + w] =
            (unsigned)f2bf(t3l[2 * tid]) | ((unsigned)f2bf(t3l[2 * tid + 1]) << 16);
    }
}

// ---------------- GEMM: out[n][4096] = t3 @ Wco^T + epilogue ----------------
// 256x256 tile, BK=64, 8 waves (2m x 4n, each 128x64 out), 128 KB LDS dbuf.
// T3+T4: raw s_barrier + counted vmcnt(8) — the next K-tile's 8 loads/wave
// stay in flight UNDER the MFMAs (no vmcnt(0) drain in the main loop).
// Inputs pre-tiled [kt][k4][row][8]: staging fully coalesced, LDS linear,
// fragment ds_read_b128 conflict-free (verified 0 conflicts in this layout).
__global__ __launch_bounds__(512, 2) void k_gemm(const __bf16* __restrict__ t3,
                                                 const __bf16* __restrict__ wco,
                                                 const float* __restrict__ pds,
                                                 const float* __restrict__ alphap,
                                                 const float* __restrict__ bias,
                                                 float* __restrict__ out) {
    __shared__ __bf16 lA[2][16384];   // [buf][k4 0..7][row 0..255][8]  2x32 KB
    __shared__ __bf16 lB[2][16384];   //                                2x32 KB

    const int tid = threadIdx.x, lane = tid & 63, wv = tid >> 6;

    // XCD-chunked bijective swizzle (1024 blocks % 8 == 0), n fastest
    const int bid = blockIdx.x;
    const int wgid = (bid & 7) * 128 + (bid >> 3);
    const int m0 = (wgid >> 4) * 256;      // 8 contiguous m-panels per XCD
    const int n0 = (wgid & 15) * 256;      // n fastest
    const int wm = wv >> 2, wn = wv & 3;   // 2 x 4 wave grid
    const int l15 = lane & 15, l4 = lane >> 4;

    // preload epilogue data (oldest VMEM ops -> drain first, counting stays valid)
    const float alpha = alphap[0];
    float pv[4], bv[4];
    #pragma unroll
    for (int nt = 0; nt < 4; ++nt) {
        const int col = n0 + wn * 64 + nt * 16 + l15;
        pv[nt] = pds[col] * alpha;
        bv[nt] = bias[col];
    }

    f32x4 acc[8][4] = {};

    // stage one K-tile (64 KB): 8 gload_lds per thread, 16 B each, coalesced
    auto stage = [&](int b, int kt) {
        #pragma unroll
        for (int i = 0; i < 4; ++i) {
            const int c = i * 512 + tid;            // 16B chunk id, 0..2047
            const int k4 = c >> 8, r = c & 255;     // k4 wave-uniform, r lane-contig
            const __bf16* ga = t3 + ((size_t)(kt * 8 + k4) * NROWS + m0 + r) * 8;
            __builtin_amdgcn_global_load_lds(
                (const __attribute__((address_space(1))) void*)ga,
                (__attribute__((address_space(3))) void*)(&lA[b][(size_t)c * 8]),
                16, 0, 0);
            const __bf16* gb = wco + ((size_t)(kt * 8 + k4) * 4096 + n0 + r) * 8;
            __builtin_amdgcn_global_load_lds(
                (const __attribute__((address_space(1))) void*)gb,
                (__attribute__((address_space(3))) void*)(&lB[b][(size_t)c * 8]),
                16, 0, 0);
        }
    };

    // one K-tile of MFMAs: 2 k-halves x (8 mt x 4 nt) = 64 per wave
    auto compute = [&](int cur) {
        #pragma unroll
        for (int kk = 0; kk < 2; ++kk) {
            const int k4f = kk * 4 + l4;
            bf16x8 bfr[4];
            #pragma unroll
            for (int nt = 0; nt < 4; ++nt)
                bfr[nt] = *(const bf16x8*)&lB[cur][(k4f * 256 + wn * 64 + nt * 16 + l15) * 8];
            #pragma unroll
            for (int mt = 0; mt < 8; ++mt) {
                bf16x8 af = *(const bf16x8*)&lA[cur][(k4f * 256 + wm * 128 + mt * 16 + l15) * 8];
                #pragma unroll
                for (int nt = 0; nt < 4; ++nt)
                    acc[mt][nt] = __builtin_amdgcn_mfma_f32_16x16x32_bf16(
                        af, bfr[nt], acc[mt][nt], 0, 0, 0);
            }
        }
    };

    stage(0, 0);     // 8 VMEM ops/wave in flight
    stage(1, 1);     // 16 in flight
    #pragma unroll 1
    for (int kt = 0; kt < 7; ++kt) {
        // wait ONLY the current tile's 8 loads; next tile's 8 stay in flight
        asm volatile("s_waitcnt vmcnt(8)" ::: "memory");
        __builtin_amdgcn_s_barrier();
        compute(kt & 1);
        __builtin_amdgcn_s_barrier();          // all waves done reading buf (kt&1)
        if (kt < 6) stage(kt & 1, kt + 2);     // refill it, 2-deep pipeline
    }
    asm volatile("s_waitcnt vmcnt(0)" ::: "memory");   // last tile: full drain
    __builtin_amdgcn_s_barrier();
    compute(1);

    // epilogue: scale * alpha + bias
    #pragma unroll
    for (int nt = 0; nt < 4; ++nt) {
        const int col = n0 + wn * 64 + nt * 16 + l15;
        #pragma unroll
        for (int mt = 0; mt < 8; ++mt) {
            const int row = m0 + wm * 128 + mt * 16 + l4 * 4;
            #pragma unroll
            for (int j = 0; j < 4; ++j)
                out[(size_t)(row + j) * 4096 + col] = acc[mt][nt][j] * pv[nt] + bv[nt];
        }
    }
}

extern "C" void kernel_launch(void* const* d_in, const int* in_sizes, int n_in,
                              void* d_out, int out_size, void* d_ws, size_t ws_size,
                              hipStream_t stream) {
    const float* x     = (const float*)d_in[0];
    const float* core  = (const float*)d_in[1];
    const float* fi0   = (const float*)d_in[2];
    const float* fi1   = (const float*)d_in[3];
    const float* fi2   = (const float*)d_in[4];
    const float* fo0   = (const float*)d_in[5];
    const float* fo1   = (const float*)d_in[6];
    const float* fo2   = (const float*)d_in[7];
    const float* pds   = (const float*)d_in[8];
    const float* alpha = (const float*)d_in[9];
    const float* bias  = (const float*)d_in[10];
    const int*   perm  = (const int*)d_in[11];
    float* outp = (float*)d_out;

    char* ws = (char*)d_ws;
    int*          inv  = (int*)(ws);                         // 16 KB
    float*        c1   = (float*)(ws + 16384);               // 2 MB
    float*        c2   = (float*)(ws + 16384 + 2097152);     // 4 MB
    unsigned int* wco  = (unsigned int*)(ws + 16384 + 2097152 + 4194304);   // 4 MB
    unsigned int* t3ws = (unsigned int*)(ws + 16384 + 2097152 + 8388608);   // 16 MB

    k_inv_perm<<<16, 256, 0, stream>>>(perm, inv);
    k_b1<<<2048, 256, 0, stream>>>(core, fo0, c1);
    k_b2<<<4096, 256, 0, stream>>>(c1, fo1, c2);
    k_b3<<<4096, 256, 0, stream>>>(c2, fo2, wco);
    k_t3<<<NROWS, 256, 0, stream>>>(x, fi0, fi1, fi2, inv, t3ws);
    k_gemm<<<1024, 512, 0, stream>>>((const __bf16*)t3ws, (const __bf16*)wco,
                                     pds, alpha, bias, outp);
}

// Round 8
// 231.983 us; speedup vs baseline: 1.2335x; 1.1184x over previous
//
#include <hip/hip_runtime.h>
#include <stdint.h>

#define NROWS 16384
#define D 4096

typedef __bf16 bf16x8 __attribute__((ext_vector_type(8)));
typedef float  f32x4  __attribute__((ext_vector_type(4)));

__device__ inline unsigned short f2bf(float f) {
    unsigned u = __float_as_uint(f);
    u += 0x7fffu + ((u >> 16) & 1u);
    return (unsigned short)(u >> 16);
}

// ---------------- Wco build: c1[X][y][z][pqr] = sum_x fo0[X,x] core[x,y,z,pqr]
__global__ __launch_bounds__(256) void k_b1(const float* __restrict__ core,
                                            const float* __restrict__ fo0,
                                            float* __restrict__ c1) {
    int g = blockIdx.x * 256 + threadIdx.x;      // 524288
    int pqr = g & 511, z = (g >> 9) & 7, y = (g >> 12) & 7, X = g >> 15;
    float s = 0.f;
    #pragma unroll
    for (int x = 0; x < 8; ++x)
        s += fo0[X * 8 + x] * core[x * 32768 + y * 4096 + z * 512 + pqr];
    c1[g] = s;
}

// c2[X][Y][z][pqr] = sum_y fo1[Y,y] c1[X,y,z,pqr]
__global__ __launch_bounds__(256) void k_b2(const float* __restrict__ c1,
                                            const float* __restrict__ fo1,
                                            float* __restrict__ c2) {
    int g = blockIdx.x * 256 + threadIdx.x;      // 1048576
    int pqr = g & 511, z = (g >> 9) & 7, Y = (g >> 12) & 15, X = g >> 16;
    float s = 0.f;
    #pragma unroll
    for (int y = 0; y < 8; ++y)
        s += fo1[Y * 8 + y] * c1[X * 32768 + y * 4096 + z * 512 + pqr];
    c2[g] = s;
}

// Wco in GEMM staging layout [kt][k4][n][8bf16] (u32-pair granularity)
__global__ __launch_bounds__(256) void k_b3(const float* __restrict__ c2,
                                            const float* __restrict__ fo2,
                                            unsigned int* __restrict__ wco) {
    int g = blockIdx.x * 256 + threadIdx.x;      // 1048576
    int kp = g & 255, n = g >> 8;                // kp = bf16-pair index, k=2*kp
    int X = n >> 8, Y = (n >> 4) & 15, Z = n & 15;
    float s0 = 0.f, s1 = 0.f;
    #pragma unroll
    for (int z = 0; z < 8; ++z) {
        float2 v = *(const float2*)&c2[X * 65536 + Y * 4096 + z * 512 + 2 * kp];
        float f = fo2[Z * 8 + z];
        s0 += f * v.x; s1 += f * v.y;
    }
    const int kt = kp >> 5, k4 = (kp >> 2) & 7, w = kp & 3;
    wco[(((size_t)kt * 8 + k4) * 4096 + n) * 4 + w] =
        (unsigned)f2bf(s0) | ((unsigned)f2bf(s1) << 16);
}

// ---------------- input contraction: 4 rows/block, dbuf pipeline ----------------
// t3 stored in GEMM staging layout [kt][k4][n][8bf16].
// Per-wave VMEM issue counts are UNIFORM (fac 3, pj 16, stage 4, store 1/row)
// so counted vmcnt gates are valid. Raw s_barrier + lgkmcnt(0) inner barriers
// keep prefetched gload_lds in flight across phases.
__global__ __launch_bounds__(256, 3) void k_t3(const float* __restrict__ x,
                                               const float* __restrict__ fi0,
                                               const float* __restrict__ fi1,
                                               const float* __restrict__ fi2,
                                               const int* __restrict__ perm,
                                               unsigned int* __restrict__ t3out) {
    __shared__ float xr[2][4096];  // 32 KB, double-buffered un-permuted rows
    __shared__ float t1[2048];     //  8 KB
    __shared__ float t2[1024];     //  4 KB
    __shared__ float fac[3][128];  //  1.5 KB

    const int tid = threadIdx.x, wv = tid >> 6;
    const int n0 = blockIdx.x * 4;

    // factors -> LDS (3 VMEM loads per thread, wave-uniform count; redundant
    // same-value writes across tid halves are benign)
    {
        const int h = tid & 127;
        fac[0][h] = fi0[h];
        fac[1][h] = fi1[h];
        fac[2][h] = fi2[h];
    }
    // permutation gather indices for step 3 (16 VMEM loads, L2-hot)
    int pj[16];
    #pragma unroll
    for (int j = 0; j < 16; ++j) pj[j] = perm[j * 256 + tid];

    // stage one row linearly into xr[b]: 4 gload_lds x 16 B, coalesced
    auto stage = [&](int b, int row) {
        const float4* src = (const float4*)(x + (size_t)row * D);
        #pragma unroll
        for (int i = 0; i < 4; ++i) {
            const int c = i * 256 + tid;   // float4 chunk 0..1023
            __builtin_amdgcn_global_load_lds(
                (const __attribute__((address_space(1))) void*)(src + c),
                (__attribute__((address_space(3))) void*)(&xr[b][c * 4]),
                16, 0, 0);
        }
    };

    // phases (bodies identical to the verified round-4 kernel, xr gathered via pj)
    auto STEP3 = [&](int b) {
        float a8[8] = {0,0,0,0,0,0,0,0};
        #pragma unroll
        for (int a = 0; a < 16; ++a) {
            float v = xr[b][pj[a]];
            #pragma unroll
            for (int p = 0; p < 8; ++p) a8[p] += v * fac[0][a * 8 + p];
        }
        #pragma unroll
        for (int p = 0; p < 8; ++p) t1[p * 256 + tid] = a8[p];
    };
    auto STEP4 = [&]() {
        const int p = tid >> 5, c = (tid >> 1) & 15, qh = tid & 1;
        float a4[4] = {0,0,0,0};
        #pragma unroll
        for (int b = 0; b < 16; ++b) {
            float v = t1[p * 256 + b * 16 + c];
            #pragma unroll
            for (int qi = 0; qi < 4; ++qi) a4[qi] += v * fac[1][b * 8 + qh * 4 + qi];
        }
        #pragma unroll
        for (int qi = 0; qi < 4; ++qi) t2[p * 128 + (qh * 4 + qi) * 16 + c] = a4[qi];
    };
    auto STEP5_PACK = [&](int n) {
        const int p = tid >> 5, q = (tid >> 2) & 7, rh = tid & 3;
        float a2[2] = {0,0};
        #pragma unroll
        for (int c = 0; c < 16; ++c) {
            float v = t2[p * 128 + q * 16 + c];
            #pragma unroll
            for (int ri = 0; ri < 2; ++ri) a2[ri] += v * fac[2][c * 8 + rh * 2 + ri];
        }
        // t3l index 2*tid == this thread's own values -> pack directly
        const int kt = tid >> 5, k4 = (tid >> 2) & 7, w = tid & 3;
        t3out[(((size_t)kt * 8 + k4) * NROWS + n) * 4 + w] =
            (unsigned)f2bf(a2[0]) | ((unsigned)f2bf(a2[1]) << 16);
    };

    stage(0, n0 + 0);   // 4 VMEM
    stage(1, n0 + 1);   // 4 VMEM

    // ---- row 0 ----  (gate: S1's 4 newest outstanding allowed; also drain fac ds_writes)
    asm volatile("s_waitcnt vmcnt(4) lgkmcnt(0)" ::: "memory");
    __builtin_amdgcn_s_barrier();
    STEP3(0);
    asm volatile("s_waitcnt lgkmcnt(0)" ::: "memory");
    __builtin_amdgcn_s_barrier();
    stage(0, n0 + 2);                      // xr[0] free now; +4 VMEM
    STEP4();
    asm volatile("s_waitcnt lgkmcnt(0)" ::: "memory");
    __builtin_amdgcn_s_barrier();
    STEP5_PACK(n0 + 0);                    // +1 VMEM store

    // ---- row 1 ----  (need S1 done; newer: S2(4)+store0(1) = 5)
    asm volatile("s_waitcnt vmcnt(5)" ::: "memory");
    __builtin_amdgcn_s_barrier();
    STEP3(1);
    asm volatile("s_waitcnt lgkmcnt(0)" ::: "memory");
    __builtin_amdgcn_s_barrier();
    stage(1, n0 + 3);                      // +4 VMEM
    STEP4();
    asm volatile("s_waitcnt lgkmcnt(0)" ::: "memory");
    __builtin_amdgcn_s_barrier();
    STEP5_PACK(n0 + 1);                    // +1 VMEM store

    // ---- row 2 ----  (need S2 done; newer: store0+S3(4)+store1 = 6)
    asm volatile("s_waitcnt vmcnt(6)" ::: "memory");
    __builtin_amdgcn_s_barrier();
    STEP3(0);
    asm volatile("s_waitcnt lgkmcnt(0)" ::: "memory");
    __builtin_amdgcn_s_barrier();
    STEP4();
    asm volatile("s_waitcnt lgkmcnt(0)" ::: "memory");
    __builtin_amdgcn_s_barrier();
    STEP5_PACK(n0 + 2);                    // +1 VMEM store

    // ---- row 3 ----  (need S3 done; newer: store1+store2 = 2)
    asm volatile("s_waitcnt vmcnt(2)" ::: "memory");
    __builtin_amdgcn_s_barrier();
    STEP3(1);
    asm volatile("s_waitcnt lgkmcnt(0)" ::: "memory");
    __builtin_amdgcn_s_barrier();
    STEP4();
    asm volatile("s_waitcnt lgkmcnt(0)" ::: "memory");
    __builtin_amdgcn_s_barrier();
    STEP5_PACK(n0 + 3);
}

// ---------------- GEMM: out[n][4096] = t3 @ Wco^T + epilogue ----------------
// Round-4 kernel verbatim; only change: launch_bounds (256,2) -> (256,4).
__global__ __launch_bounds__(256, 4) void k_gemm(const __bf16* __restrict__ t3,
                                                 const __bf16* __restrict__ wco,
                                                 const float* __restrict__ pds,
                                                 const float* __restrict__ alphap,
                                                 const float* __restrict__ bias,
                                                 float* __restrict__ out) {
    __shared__ __bf16 lA[8192];   // [k4 0..7][row 0..127][8]  16 KB
    __shared__ __bf16 lB[8192];   // same for B               16 KB

    const int tid = threadIdx.x, lane = tid & 63, wv = tid >> 6;

    // XCD-chunked bijective swizzle, n fastest (A-panel L2-hot per XCD)
    const int bid = blockIdx.x;
    const int wgid = (bid & 7) * 512 + (bid >> 3);
    const int m0 = (wgid >> 5) * 128;      // 16 contiguous m-panels per XCD
    const int n0 = (wgid & 31) * 128;      // n fastest
    const int wm = wv >> 1, wn = wv & 1;
    const int l15 = lane & 15, l4 = lane >> 4;

    // preload epilogue data (hidden under the K-loop)
    const float alpha = alphap[0];
    float pv[4], bv[4];
    #pragma unroll
    for (int nt = 0; nt < 4; ++nt) {
        const int col = n0 + wn * 64 + nt * 16 + l15;
        pv[nt] = pds[col] * alpha;
        bv[nt] = bias[col];
    }

    f32x4 acc[4][4] = {};

    for (int ks = 0; ks < 8; ++ks) {
        #pragma unroll
        for (int i = 0; i < 4; ++i) {
            const int c = i * 256 + tid;            // 16B chunk id, 0..1023
            const int k4 = c >> 7, r = c & 127;     // k4 wave-uniform, r=lane-contig
            const __bf16* ga = t3 + ((size_t)(ks * 8 + k4) * NROWS + m0 + r) * 8;
            __builtin_amdgcn_global_load_lds(
                (const __attribute__((address_space(1))) void*)ga,
                (__attribute__((address_space(3))) void*)(lA + (size_t)c * 8),
                16, 0, 0);
            const __bf16* gb = wco + ((size_t)(ks * 8 + k4) * 4096 + n0 + r) * 8;
            __builtin_amdgcn_global_load_lds(
                (const __attribute__((address_space(1))) void*)gb,
                (__attribute__((address_space(3))) void*)(lB + (size_t)c * 8),
                16, 0, 0);
        }
        __syncthreads();
        #pragma unroll
        for (int kk = 0; kk < 2; ++kk) {
            const int k4f = kk * 4 + l4;
            bf16x8 af[4], bfr[4];
            #pragma unroll
            for (int mt = 0; mt < 4; ++mt)
                af[mt] = *(const bf16x8*)&lA[(k4f * 128 + wm * 64 + mt * 16 + l15) * 8];
            #pragma unroll
            for (int nt = 0; nt < 4; ++nt)
                bfr[nt] = *(const bf16x8*)&lB[(k4f * 128 + wn * 64 + nt * 16 + l15) * 8];
            #pragma unroll
            for (int mt = 0; mt < 4; ++mt)
                #pragma unroll
                for (int nt = 0; nt < 4; ++nt)
                    acc[mt][nt] = __builtin_amdgcn_mfma_f32_16x16x32_bf16(
                        af[mt], bfr[nt], acc[mt][nt], 0, 0, 0);
        }
        __syncthreads();
    }

    // epilogue: scale * alpha + bias
    #pragma unroll
    for (int nt = 0; nt < 4; ++nt) {
        const int col = n0 + wn * 64 + nt * 16 + l15;
        #pragma unroll
        for (int mt = 0; mt < 4; ++mt) {
            const int row = m0 + wm * 64 + mt * 16 + l4 * 4;
            #pragma unroll
            for (int j = 0; j < 4; ++j)
                out[(size_t)(row + j) * 4096 + col] = acc[mt][nt][j] * pv[nt] + bv[nt];
        }
    }
}

extern "C" void kernel_launch(void* const* d_in, const int* in_sizes, int n_in,
                              void* d_out, int out_size, void* d_ws, size_t ws_size,
                              hipStream_t stream) {
    const float* x     = (const float*)d_in[0];
    const float* core  = (const float*)d_in[1];
    const float* fi0   = (const float*)d_in[2];
    const float* fi1   = (const float*)d_in[3];
    const float* fi2   = (const float*)d_in[4];
    const float* fo0   = (const float*)d_in[5];
    const float* fo1   = (const float*)d_in[6];
    const float* fo2   = (const float*)d_in[7];
    const float* pds   = (const float*)d_in[8];
    const float* alpha = (const float*)d_in[9];
    const float* bias  = (const float*)d_in[10];
    const int*   perm  = (const int*)d_in[11];
    float* outp = (float*)d_out;

    char* ws = (char*)d_ws;
    float*        c1   = (float*)(ws);                       // 2 MB
    float*        c2   = (float*)(ws + 2097152);             // 4 MB
    unsigned int* wco  = (unsigned int*)(ws + 6291456);      // 4 MB
    unsigned int* t3ws = (unsigned int*)(ws + 10485760);     // 16 MB

    k_b1<<<2048, 256, 0, stream>>>(core, fo0, c1);
    k_b2<<<4096, 256, 0, stream>>>(c1, fo1, c2);
    k_b3<<<4096, 256, 0, stream>>>(c2, fo2, wco);
    k_t3<<<NROWS / 4, 256, 0, stream>>>(x, fi0, fi1, fi2, perm, t3ws);
    k_gemm<<<4096, 256, 0, stream>>>((const __bf16*)t3ws, (const __bf16*)wco,
                                     pds, alpha, bias, outp);
}

// Round 9
// 228.665 us; speedup vs baseline: 1.2514x; 1.0145x over previous
//
#include <hip/hip_runtime.h>
#include <stdint.h>

#define NROWS 16384
#define D 4096

typedef __bf16 bf16x8 __attribute__((ext_vector_type(8)));
typedef float  f32x4  __attribute__((ext_vector_type(4)));

__device__ inline unsigned short f2bf(float f) {
    unsigned u = __float_as_uint(f);
    u += 0x7fffu + ((u >> 16) & 1u);
    return (unsigned short)(u >> 16);
}

// ---------------- Wco build: c1[X][y][z][pqr] = sum_x fo0[X,x] core[x,y,z,pqr]
__global__ __launch_bounds__(256) void k_b1(const float* __restrict__ core,
                                            const float* __restrict__ fo0,
                                            float* __restrict__ c1) {
    int g = blockIdx.x * 256 + threadIdx.x;      // 524288
    int pqr = g & 511, z = (g >> 9) & 7, y = (g >> 12) & 7, X = g >> 15;
    float s = 0.f;
    #pragma unroll
    for (int x = 0; x < 8; ++x)
        s += fo0[X * 8 + x] * core[x * 32768 + y * 4096 + z * 512 + pqr];
    c1[g] = s;
}

// c2[X][Y][z][pqr] = sum_y fo1[Y,y] c1[X,y,z,pqr]
__global__ __launch_bounds__(256) void k_b2(const float* __restrict__ c1,
                                            const float* __restrict__ fo1,
                                            float* __restrict__ c2) {
    int g = blockIdx.x * 256 + threadIdx.x;      // 1048576
    int pqr = g & 511, z = (g >> 9) & 7, Y = (g >> 12) & 15, X = g >> 16;
    float s = 0.f;
    #pragma unroll
    for (int y = 0; y < 8; ++y)
        s += fo1[Y * 8 + y] * c1[X * 32768 + y * 4096 + z * 512 + pqr];
    c2[g] = s;
}

// Wco in GEMM staging layout [kt][k4][n][8bf16] (u32-pair granularity)
__global__ __launch_bounds__(256) void k_b3(const float* __restrict__ c2,
                                            const float* __restrict__ fo2,
                                            unsigned int* __restrict__ wco) {
    int g = blockIdx.x * 256 + threadIdx.x;      // 1048576
    int kp = g & 255, n = g >> 8;                // kp = bf16-pair index, k=2*kp
    int X = n >> 8, Y = (n >> 4) & 15, Z = n & 15;
    float s0 = 0.f, s1 = 0.f;
    #pragma unroll
    for (int z = 0; z < 8; ++z) {
        float2 v = *(const float2*)&c2[X * 65536 + Y * 4096 + z * 512 + 2 * kp];
        float f = fo2[Z * 8 + z];
        s0 += f * v.x; s1 += f * v.y;
    }
    const int kt = kp >> 5, k4 = (kp >> 2) & 7, w = kp & 3;
    wco[(((size_t)kt * 8 + k4) * 4096 + n) * 4 + w] =
        (unsigned)f2bf(s0) | ((unsigned)f2bf(s1) << 16);
}

// ---------------- input contraction: 4 rows/block, dbuf pipeline ----------------
// (byte-identical to round 8 — verified)
__global__ __launch_bounds__(256, 3) void k_t3(const float* __restrict__ x,
                                               const float* __restrict__ fi0,
                                               const float* __restrict__ fi1,
                                               const float* __restrict__ fi2,
                                               const int* __restrict__ perm,
                                               unsigned int* __restrict__ t3out) {
    __shared__ float xr[2][4096];  // 32 KB, double-buffered un-permuted rows
    __shared__ float t1[2048];     //  8 KB
    __shared__ float t2[1024];     //  4 KB
    __shared__ float fac[3][128];  //  1.5 KB

    const int tid = threadIdx.x;
    const int n0 = blockIdx.x * 4;

    {
        const int h = tid & 127;
        fac[0][h] = fi0[h];
        fac[1][h] = fi1[h];
        fac[2][h] = fi2[h];
    }
    int pj[16];
    #pragma unroll
    for (int j = 0; j < 16; ++j) pj[j] = perm[j * 256 + tid];

    auto stage = [&](int b, int row) {
        const float4* src = (const float4*)(x + (size_t)row * D);
        #pragma unroll
        for (int i = 0; i < 4; ++i) {
            const int c = i * 256 + tid;
            __builtin_amdgcn_global_load_lds(
                (const __attribute__((address_space(1))) void*)(src + c),
                (__attribute__((address_space(3))) void*)(&xr[b][c * 4]),
                16, 0, 0);
        }
    };

    auto STEP3 = [&](int b) {
        float a8[8] = {0,0,0,0,0,0,0,0};
        #pragma unroll
        for (int a = 0; a < 16; ++a) {
            float v = xr[b][pj[a]];
            #pragma unroll
            for (int p = 0; p < 8; ++p) a8[p] += v * fac[0][a * 8 + p];
        }
        #pragma unroll
        for (int p = 0; p < 8; ++p) t1[p * 256 + tid] = a8[p];
    };
    auto STEP4 = [&]() {
        const int p = tid >> 5, c = (tid >> 1) & 15, qh = tid & 1;
        float a4[4] = {0,0,0,0};
        #pragma unroll
        for (int b = 0; b < 16; ++b) {
            float v = t1[p * 256 + b * 16 + c];
            #pragma unroll
            for (int qi = 0; qi < 4; ++qi) a4[qi] += v * fac[1][b * 8 + qh * 4 + qi];
        }
        #pragma unroll
        for (int qi = 0; qi < 4; ++qi) t2[p * 128 + (qh * 4 + qi) * 16 + c] = a4[qi];
    };
    auto STEP5_PACK = [&](int n) {
        const int p = tid >> 5, q = (tid >> 2) & 7, rh = tid & 3;
        float a2[2] = {0,0};
        #pragma unroll
        for (int c = 0; c < 16; ++c) {
            float v = t2[p * 128 + q * 16 + c];
            #pragma unroll
            for (int ri = 0; ri < 2; ++ri) a2[ri] += v * fac[2][c * 8 + rh * 2 + ri];
        }
        const int kt = tid >> 5, k4 = (tid >> 2) & 7, w = tid & 3;
        t3out[(((size_t)kt * 8 + k4) * NROWS + n) * 4 + w] =
            (unsigned)f2bf(a2[0]) | ((unsigned)f2bf(a2[1]) << 16);
    };

    stage(0, n0 + 0);
    stage(1, n0 + 1);

    asm volatile("s_waitcnt vmcnt(4) lgkmcnt(0)" ::: "memory");
    __builtin_amdgcn_s_barrier();
    STEP3(0);
    asm volatile("s_waitcnt lgkmcnt(0)" ::: "memory");
    __builtin_amdgcn_s_barrier();
    stage(0, n0 + 2);
    STEP4();
    asm volatile("s_waitcnt lgkmcnt(0)" ::: "memory");
    __builtin_amdgcn_s_barrier();
    STEP5_PACK(n0 + 0);

    asm volatile("s_waitcnt vmcnt(5)" ::: "memory");
    __builtin_amdgcn_s_barrier();
    STEP3(1);
    asm volatile("s_waitcnt lgkmcnt(0)" ::: "memory");
    __builtin_amdgcn_s_barrier();
    stage(1, n0 + 3);
    STEP4();
    asm volatile("s_waitcnt lgkmcnt(0)" ::: "memory");
    __builtin_amdgcn_s_barrier();
    STEP5_PACK(n0 + 1);

    asm volatile("s_waitcnt vmcnt(6)" ::: "memory");
    __builtin_amdgcn_s_barrier();
    STEP3(0);
    asm volatile("s_waitcnt lgkmcnt(0)" ::: "memory");
    __builtin_amdgcn_s_barrier();
    STEP4();
    asm volatile("s_waitcnt lgkmcnt(0)" ::: "memory");
    __builtin_amdgcn_s_barrier();
    STEP5_PACK(n0 + 2);

    asm volatile("s_waitcnt vmcnt(2)" ::: "memory");
    __builtin_amdgcn_s_barrier();
    STEP3(1);
    asm volatile("s_waitcnt lgkmcnt(0)" ::: "memory");
    __builtin_amdgcn_s_barrier();
    STEP4();
    asm volatile("s_waitcnt lgkmcnt(0)" ::: "memory");
    __builtin_amdgcn_s_barrier();
    STEP5_PACK(n0 + 3);
}

// ---------------- GEMM: out[n][4096] = t3 @ Wco^T + epilogue ----------------
// 128x128 tile, BK=64, 4 waves, T3+T4 counted-vmcnt double-buffer:
// stage(kt+2) issued after the buffer-free barrier; gate vmcnt(8) waits ONLY
// the current tile's 8 loads/lane — next tile's 8 stay in flight under the
// MFMAs. 64 KB LDS -> 2 blocks/CU preserved for epilogue/prologue overlap.
__global__ __launch_bounds__(256, 2) void k_gemm(const __bf16* __restrict__ t3,
                                                 const __bf16* __restrict__ wco,
                                                 const float* __restrict__ pds,
                                                 const float* __restrict__ alphap,
                                                 const float* __restrict__ bias,
                                                 float* __restrict__ out) {
    __shared__ __bf16 lA[2][8192];   // [buf][k4][row][8]  2x16 KB
    __shared__ __bf16 lB[2][8192];   //                    2x16 KB

    const int tid = threadIdx.x, lane = tid & 63, wv = tid >> 6;

    // XCD-chunked bijective swizzle, n fastest (A-panel L2-hot per XCD)
    const int bid = blockIdx.x;
    const int wgid = (bid & 7) * 512 + (bid >> 3);
    const int m0 = (wgid >> 5) * 128;
    const int n0 = (wgid & 31) * 128;
    const int wm = wv >> 1, wn = wv & 1;
    const int l15 = lane & 15, l4 = lane >> 4;

    // epilogue preload (8 VMEM/lane, OLDEST — drained by the first gate)
    const float alpha = alphap[0];
    float pv[4], bv[4];
    #pragma unroll
    for (int nt = 0; nt < 4; ++nt) {
        const int col = n0 + wn * 64 + nt * 16 + l15;
        pv[nt] = pds[col] * alpha;
        bv[nt] = bias[col];
    }

    // stage one K-tile into buf b: 8 gload_lds/lane, 16 B each, coalesced
    auto stage = [&](int b, int kt) {
        #pragma unroll
        for (int i = 0; i < 4; ++i) {
            const int c = i * 256 + tid;            // 16B chunk id, 0..1023
            const int k4 = c >> 7, r = c & 127;
            const __bf16* ga = t3 + ((size_t)(kt * 8 + k4) * NROWS + m0 + r) * 8;
            __builtin_amdgcn_global_load_lds(
                (const __attribute__((address_space(1))) void*)ga,
                (__attribute__((address_space(3))) void*)(&lA[b][(size_t)c * 8]),
                16, 0, 0);
            const __bf16* gb = wco + ((size_t)(kt * 8 + k4) * 4096 + n0 + r) * 8;
            __builtin_amdgcn_global_load_lds(
                (const __attribute__((address_space(1))) void*)gb,
                (__attribute__((address_space(3))) void*)(&lB[b][(size_t)c * 8]),
                16, 0, 0);
        }
    };

    f32x4 acc[4][4] = {};

    auto compute = [&](int cur) {
        #pragma unroll
        for (int kk = 0; kk < 2; ++kk) {
            const int k4f = kk * 4 + l4;
            bf16x8 af[4], bfr[4];
            #pragma unroll
            for (int mt = 0; mt < 4; ++mt)
                af[mt] = *(const bf16x8*)&lA[cur][(k4f * 128 + wm * 64 + mt * 16 + l15) * 8];
            #pragma unroll
            for (int nt = 0; nt < 4; ++nt)
                bfr[nt] = *(const bf16x8*)&lB[cur][(k4f * 128 + wn * 64 + nt * 16 + l15) * 8];
            #pragma unroll
            for (int mt = 0; mt < 4; ++mt)
                #pragma unroll
                for (int nt = 0; nt < 4; ++nt)
                    acc[mt][nt] = __builtin_amdgcn_mfma_f32_16x16x32_bf16(
                        af[mt], bfr[nt], acc[mt][nt], 0, 0, 0);
        }
    };

    stage(0, 0);     // 8 VMEM/lane in flight
    stage(1, 1);     // 16 in flight (+8 pv/bv older)
    #pragma unroll 1
    for (int kt = 0; kt < 8; ++kt) {
        if (kt < 7) asm volatile("s_waitcnt vmcnt(8)" ::: "memory");
        else        asm volatile("s_waitcnt vmcnt(0)" ::: "memory");
        __builtin_amdgcn_s_barrier();          // all waves: tile kt resident
        __builtin_amdgcn_s_setprio(1);
        compute(kt & 1);
        __builtin_amdgcn_s_setprio(0);
        __builtin_amdgcn_s_barrier();          // all waves done reading buf
        if (kt < 6) stage(kt & 1, kt + 2);     // refill freed buffer, 2-deep
    }

    // epilogue: scale * alpha + bias
    #pragma unroll
    for (int nt = 0; nt < 4; ++nt) {
        const int col = n0 + wn * 64 + nt * 16 + l15;
        #pragma unroll
        for (int mt = 0; mt < 4; ++mt) {
            const int row = m0 + wm * 64 + mt * 16 + l4 * 4;
            #pragma unroll
            for (int j = 0; j < 4; ++j)
                out[(size_t)(row + j) * 4096 + col] = acc[mt][nt][j] * pv[nt] + bv[nt];
        }
    }
}

extern "C" void kernel_launch(void* const* d_in, const int* in_sizes, int n_in,
                              void* d_out, int out_size, void* d_ws, size_t ws_size,
                              hipStream_t stream) {
    const float* x     = (const float*)d_in[0];
    const float* core  = (const float*)d_in[1];
    const float* fi0   = (const float*)d_in[2];
    const float* fi1   = (const float*)d_in[3];
    const float* fi2   = (const float*)d_in[4];
    const float* fo0   = (const float*)d_in[5];
    const float* fo1   = (const float*)d_in[6];
    const float* fo2   = (const float*)d_in[7];
    const float* pds   = (const float*)d_in[8];
    const float* alpha = (const float*)d_in[9];
    const float* bias  = (const float*)d_in[10];
    const int*   perm  = (const int*)d_in[11];
    float* outp = (float*)d_out;

    char* ws = (char*)d_ws;
    float*        c1   = (float*)(ws);                       // 2 MB
    float*        c2   = (float*)(ws + 2097152);             // 4 MB
    unsigned int* wco  = (unsigned int*)(ws + 6291456);      // 4 MB
    unsigned int* t3ws = (unsigned int*)(ws + 10485760);     // 16 MB

    k_b1<<<2048, 256, 0, stream>>>(core, fo0, c1);
    k_b2<<<4096, 256, 0, stream>>>(c1, fo1, c2);
    k_b3<<<4096, 256, 0, stream>>>(c2, fo2, wco);
    k_t3<<<NROWS / 4, 256, 0, stream>>>(x, fi0, fi1, fi2, perm, t3ws);
    k_gemm<<<4096, 256, 0, stream>>>((const __bf16*)t3ws, (const __bf16*)wco,
                                     pds, alpha, bias, outp);
}

// Round 10
// 221.672 us; speedup vs baseline: 1.2909x; 1.0315x over previous
//
#include <hip/hip_runtime.h>
#include <stdint.h>

#define NROWS 16384
#define D 4096

typedef __bf16 bf16x8 __attribute__((ext_vector_type(8)));
typedef float  f32x4  __attribute__((ext_vector_type(4)));

__device__ inline unsigned short f2bf(float f) {
    unsigned u = __float_as_uint(f);
    u += 0x7fffu + ((u >> 16) & 1u);
    return (unsigned short)(u >> 16);
}

// ---------------- Wco build: c1[X][y][z][pqr] = sum_x fo0[X,x] core[x,y,z,pqr]
__global__ __launch_bounds__(256) void k_b1(const float* __restrict__ core,
                                            const float* __restrict__ fo0,
                                            float* __restrict__ c1) {
    int g = blockIdx.x * 256 + threadIdx.x;      // 524288
    int pqr = g & 511, z = (g >> 9) & 7, y = (g >> 12) & 7, X = g >> 15;
    float s = 0.f;
    #pragma unroll
    for (int x = 0; x < 8; ++x)
        s += fo0[X * 8 + x] * core[x * 32768 + y * 4096 + z * 512 + pqr];
    c1[g] = s;
}

// c2[X][Y][z][pqr] = sum_y fo1[Y,y] c1[X,y,z,pqr]
__global__ __launch_bounds__(256) void k_b2(const float* __restrict__ c1,
                                            const float* __restrict__ fo1,
                                            float* __restrict__ c2) {
    int g = blockIdx.x * 256 + threadIdx.x;      // 1048576
    int pqr = g & 511, z = (g >> 9) & 7, Y = (g >> 12) & 15, X = g >> 16;
    float s = 0.f;
    #pragma unroll
    for (int y = 0; y < 8; ++y)
        s += fo1[Y * 8 + y] * c1[X * 32768 + y * 4096 + z * 512 + pqr];
    c2[g] = s;
}

// Wco in GEMM staging layout [kt][k4][n][8bf16] (u32-pair granularity)
__global__ __launch_bounds__(256) void k_b3(const float* __restrict__ c2,
                                            const float* __restrict__ fo2,
                                            unsigned int* __restrict__ wco) {
    int g = blockIdx.x * 256 + threadIdx.x;      // 1048576
    int kp = g & 255, n = g >> 8;                // kp = bf16-pair index, k=2*kp
    int X = n >> 8, Y = (n >> 4) & 15, Z = n & 15;
    float s0 = 0.f, s1 = 0.f;
    #pragma unroll
    for (int z = 0; z < 8; ++z) {
        float2 v = *(const float2*)&c2[X * 65536 + Y * 4096 + z * 512 + 2 * kp];
        float f = fo2[Z * 8 + z];
        s0 += f * v.x; s1 += f * v.y;
    }
    const int kt = kp >> 5, k4 = (kp >> 2) & 7, w = kp & 3;
    wco[(((size_t)kt * 8 + k4) * 4096 + n) * 4 + w] =
        (unsigned)f2bf(s0) | ((unsigned)f2bf(s1) << 16);
}

// ---------------- input contraction: 4 rows/block, dbuf pipeline ----------------
// (byte-identical to rounds 8/9 — verified)
__global__ __launch_bounds__(256, 3) void k_t3(const float* __restrict__ x,
                                               const float* __restrict__ fi0,
                                               const float* __restrict__ fi1,
                                               const float* __restrict__ fi2,
                                               const int* __restrict__ perm,
                                               unsigned int* __restrict__ t3out) {
    __shared__ float xr[2][4096];  // 32 KB, double-buffered un-permuted rows
    __shared__ float t1[2048];     //  8 KB
    __shared__ float t2[1024];     //  4 KB
    __shared__ float fac[3][128];  //  1.5 KB

    const int tid = threadIdx.x;
    const int n0 = blockIdx.x * 4;

    {
        const int h = tid & 127;
        fac[0][h] = fi0[h];
        fac[1][h] = fi1[h];
        fac[2][h] = fi2[h];
    }
    int pj[16];
    #pragma unroll
    for (int j = 0; j < 16; ++j) pj[j] = perm[j * 256 + tid];

    auto stage = [&](int b, int row) {
        const float4* src = (const float4*)(x + (size_t)row * D);
        #pragma unroll
        for (int i = 0; i < 4; ++i) {
            const int c = i * 256 + tid;
            __builtin_amdgcn_global_load_lds(
                (const __attribute__((address_space(1))) void*)(src + c),
                (__attribute__((address_space(3))) void*)(&xr[b][c * 4]),
                16, 0, 0);
        }
    };

    auto STEP3 = [&](int b) {
        float a8[8] = {0,0,0,0,0,0,0,0};
        #pragma unroll
        for (int a = 0; a < 16; ++a) {
            float v = xr[b][pj[a]];
            #pragma unroll
            for (int p = 0; p < 8; ++p) a8[p] += v * fac[0][a * 8 + p];
        }
        #pragma unroll
        for (int p = 0; p < 8; ++p) t1[p * 256 + tid] = a8[p];
    };
    auto STEP4 = [&]() {
        const int p = tid >> 5, c = (tid >> 1) & 15, qh = tid & 1;
        float a4[4] = {0,0,0,0};
        #pragma unroll
        for (int b = 0; b < 16; ++b) {
            float v = t1[p * 256 + b * 16 + c];
            #pragma unroll
            for (int qi = 0; qi < 4; ++qi) a4[qi] += v * fac[1][b * 8 + qh * 4 + qi];
        }
        #pragma unroll
        for (int qi = 0; qi < 4; ++qi) t2[p * 128 + (qh * 4 + qi) * 16 + c] = a4[qi];
    };
    auto STEP5_PACK = [&](int n) {
        const int p = tid >> 5, q = (tid >> 2) & 7, rh = tid & 3;
        float a2[2] = {0,0};
        #pragma unroll
        for (int c = 0; c < 16; ++c) {
            float v = t2[p * 128 + q * 16 + c];
            #pragma unroll
            for (int ri = 0; ri < 2; ++ri) a2[ri] += v * fac[2][c * 8 + rh * 2 + ri];
        }
        const int kt = tid >> 5, k4 = (tid >> 2) & 7, w = tid & 3;
        t3out[(((size_t)kt * 8 + k4) * NROWS + n) * 4 + w] =
            (unsigned)f2bf(a2[0]) | ((unsigned)f2bf(a2[1]) << 16);
    };

    stage(0, n0 + 0);
    stage(1, n0 + 1);

    asm volatile("s_waitcnt vmcnt(4) lgkmcnt(0)" ::: "memory");
    __builtin_amdgcn_s_barrier();
    STEP3(0);
    asm volatile("s_waitcnt lgkmcnt(0)" ::: "memory");
    __builtin_amdgcn_s_barrier();
    stage(0, n0 + 2);
    STEP4();
    asm volatile("s_waitcnt lgkmcnt(0)" ::: "memory");
    __builtin_amdgcn_s_barrier();
    STEP5_PACK(n0 + 0);

    asm volatile("s_waitcnt vmcnt(5)" ::: "memory");
    __builtin_amdgcn_s_barrier();
    STEP3(1);
    asm volatile("s_waitcnt lgkmcnt(0)" ::: "memory");
    __builtin_amdgcn_s_barrier();
    stage(1, n0 + 3);
    STEP4();
    asm volatile("s_waitcnt lgkmcnt(0)" ::: "memory");
    __builtin_amdgcn_s_barrier();
    STEP5_PACK(n0 + 1);

    asm volatile("s_waitcnt vmcnt(6)" ::: "memory");
    __builtin_amdgcn_s_barrier();
    STEP3(0);
    asm volatile("s_waitcnt lgkmcnt(0)" ::: "memory");
    __builtin_amdgcn_s_barrier();
    STEP4();
    asm volatile("s_waitcnt lgkmcnt(0)" ::: "memory");
    __builtin_amdgcn_s_barrier();
    STEP5_PACK(n0 + 2);

    asm volatile("s_waitcnt vmcnt(2)" ::: "memory");
    __builtin_amdgcn_s_barrier();
    STEP3(1);
    asm volatile("s_waitcnt lgkmcnt(0)" ::: "memory");
    __builtin_amdgcn_s_barrier();
    STEP4();
    asm volatile("s_waitcnt lgkmcnt(0)" ::: "memory");
    __builtin_amdgcn_s_barrier();
    STEP5_PACK(n0 + 3);
}

// ---------------- GEMM: out[n][4096] = t3 @ Wco^T + epilogue ----------------
// 256x256 tile, BK=32, 16 phases, 4-buffer LDS ring (128 KB), lag-3 staging.
// Phase t: {ds_read tile t frags; stage tile t+3; vmcnt gate for tile t+1;
// barrier; lgkmcnt(0); setprio(1); 32 MFMA; setprio(0)}.
// Gate leaves tiles t+2,t+3 (8 loads/lane) in flight -> each tile's loads get
// ~3 phases to arrive. Race-safety: stage(t+3) writes buf (t+3)%4 which held
// tile t-1; tile t-1's ds_reads sit BEFORE barrier(t-1), stage-issue after it.
// 8 waves (2m x 4n), per-wave out 128x64; traffic A 256 MB + B 256 MB (halved).
__global__ __launch_bounds__(512) void k_gemm(const __bf16* __restrict__ t3,
                                              const __bf16* __restrict__ wco,
                                              const float* __restrict__ pds,
                                              const float* __restrict__ alphap,
                                              const float* __restrict__ bias,
                                              float* __restrict__ out) {
    __shared__ __bf16 lA[4][8192];   // [buf][k4 0..3][row 0..255][8]  4x16 KB
    __shared__ __bf16 lB[4][8192];   //                                4x16 KB

    const int tid = threadIdx.x, lane = tid & 63, wv = tid >> 6;

    // XCD-chunked bijective swizzle (1024 % 8 == 0), n fastest
    const int bid = blockIdx.x;
    const int wgid = (bid & 7) * 128 + (bid >> 3);
    const int m0 = (wgid >> 4) * 256;      // 8 contiguous m-panels per XCD
    const int n0 = (wgid & 15) * 256;      // n fastest
    const int wm = wv >> 2, wn = wv & 3;   // 2 x 4 wave grid
    const int l15 = lane & 15, l4 = lane >> 4;

    // epilogue preload (8 VMEM/lane, OLDEST — drained by prologue gate)
    const float alpha = alphap[0];
    float pv[4], bv[4];
    #pragma unroll
    for (int nt = 0; nt < 4; ++nt) {
        const int col = n0 + wn * 64 + nt * 16 + l15;
        pv[nt] = pds[col] * alpha;
        bv[nt] = bias[col];
    }

    // stage one BK=32 tile (A 16 KB + B 16 KB): 4 gload_lds/lane, coalesced
    auto stage = [&](int t32) {
        const int b = t32 & 3;
        const int kb = (t32 >> 1) * 8 + (t32 & 1) * 4;   // layout k4 base
        #pragma unroll
        for (int i = 0; i < 2; ++i) {
            const int c = i * 512 + tid;            // 16B chunk id, 0..1023
            const int k4 = c >> 8, r = c & 255;     // k4 wave-uniform, r lane-contig
            const __bf16* ga = t3 + ((size_t)(kb + k4) * NROWS + m0 + r) * 8;
            __builtin_amdgcn_global_load_lds(
                (const __attribute__((address_space(1))) void*)ga,
                (__attribute__((address_space(3))) void*)(&lA[b][(size_t)c * 8]),
                16, 0, 0);
            const __bf16* gb = wco + ((size_t)(kb + k4) * 4096 + n0 + r) * 8;
            __builtin_amdgcn_global_load_lds(
                (const __attribute__((address_space(1))) void*)gb,
                (__attribute__((address_space(3))) void*)(&lB[b][(size_t)c * 8]),
                16, 0, 0);
        }
    };

    f32x4 acc[8][4] = {};

    stage(0);    // 4 VMEM/lane
    stage(1);    // 8
    stage(2);    // 12 (+8 older pv/bv)
    asm volatile("s_waitcnt vmcnt(8)" ::: "memory");   // tile 0 resident; 1,2 in flight
    __builtin_amdgcn_s_barrier();

    #pragma unroll 1
    for (int t = 0; t < 16; ++t) {
        const int buf = t & 3;
        // ds_read this tile's fragments (12 x ds_read_b128, own-wave lgkm)
        bf16x8 af[8], bfr[4];
        #pragma unroll
        for (int mt = 0; mt < 8; ++mt)
            af[mt] = *(const bf16x8*)&lA[buf][(l4 * 256 + wm * 128 + mt * 16 + l15) * 8];
        #pragma unroll
        for (int nt = 0; nt < 4; ++nt)
            bfr[nt] = *(const bf16x8*)&lB[buf][(l4 * 256 + wn * 64 + nt * 16 + l15) * 8];
        // stage tile t+3 into buf (t+3)&3 (held tile t-1, freed at barrier t-1)
        if (t + 3 < 16) stage(t + 3);
        // gate for tile t+1: allow tiles t+2,t+3 (8 loads) to stay in flight
        if (t < 13)       asm volatile("s_waitcnt vmcnt(8)" ::: "memory");
        else if (t == 13) asm volatile("s_waitcnt vmcnt(4)" ::: "memory");
        else              asm volatile("s_waitcnt vmcnt(0)" ::: "memory");
        __builtin_amdgcn_s_barrier();
        asm volatile("s_waitcnt lgkmcnt(0)" ::: "memory");
        __builtin_amdgcn_s_setprio(1);
        #pragma unroll
        for (int mt = 0; mt < 8; ++mt)
            #pragma unroll
            for (int nt = 0; nt < 4; ++nt)
                acc[mt][nt] = __builtin_amdgcn_mfma_f32_16x16x32_bf16(
                    af[mt], bfr[nt], acc[mt][nt], 0, 0, 0);
        __builtin_amdgcn_s_setprio(0);
    }

    // epilogue: scale * alpha + bias
    #pragma unroll
    for (int nt = 0; nt < 4; ++nt) {
        const int col = n0 + wn * 64 + nt * 16 + l15;
        #pragma unroll
        for (int mt = 0; mt < 8; ++mt) {
            const int row = m0 + wm * 128 + mt * 16 + l4 * 4;
            #pragma unroll
            for (int j = 0; j < 4; ++j)
                out[(size_t)(row + j) * 4096 + col] = acc[mt][nt][j] * pv[nt] + bv[nt];
        }
    }
}

extern "C" void kernel_launch(void* const* d_in, const int* in_sizes, int n_in,
                              void* d_out, int out_size, void* d_ws, size_t ws_size,
                              hipStream_t stream) {
    const float* x     = (const float*)d_in[0];
    const float* core  = (const float*)d_in[1];
    const float* fi0   = (const float*)d_in[2];
    const float* fi1   = (const float*)d_in[3];
    const float* fi2   = (const float*)d_in[4];
    const float* fo0   = (const float*)d_in[5];
    const float* fo1   = (const float*)d_in[6];
    const float* fo2   = (const float*)d_in[7];
    const float* pds   = (const float*)d_in[8];
    const float* alpha = (const float*)d_in[9];
    const float* bias  = (const float*)d_in[10];
    const int*   perm  = (const int*)d_in[11];
    float* outp = (float*)d_out;

    char* ws = (char*)d_ws;
    float*        c1   = (float*)(ws);                       // 2 MB
    float*        c2   = (float*)(ws + 2097152);             // 4 MB
    unsigned int* wco  = (unsigned int*)(ws + 6291456);      // 4 MB
    unsigned int* t3ws = (unsigned int*)(ws + 10485760);     // 16 MB

    k_b1<<<2048, 256, 0, stream>>>(core, fo0, c1);
    k_b2<<<4096, 256, 0, stream>>>(c1, fo1, c2);
    k_b3<<<4096, 256, 0, stream>>>(c2, fo2, wco);
    k_t3<<<NROWS / 4, 256, 0, stream>>>(x, fi0, fi1, fi2, perm, t3ws);
    k_gemm<<<1024, 512, 0, stream>>>((const __bf16*)t3ws, (const __bf16*)wco,
                                     pds, alpha, bias, outp);
}